// Round 1
// baseline (356.785 us; speedup 1.0000x reference)
//
#include <hip/hip_runtime.h>
#include <stdint.h>

#define L_DIM 1024
#define N_DIM 32
#define C_DIM 512
#define M_DIM (L_DIM * N_DIM)   // 32768 rows for the GEMMs
#define EPS_BN 1e-5f

typedef __attribute__((ext_vector_type(8))) short bf16x8;
typedef __attribute__((ext_vector_type(4))) float f32x4;

__device__ __forceinline__ unsigned short f2bf(float f) {
  union { float f; unsigned int u; } a; a.f = f;
  unsigned int u = a.u;
  return (unsigned short)((u + 0x7FFFu + ((u >> 16) & 1u)) >> 16); // RNE
}
__device__ __forceinline__ float bf2f(unsigned short h) {
  union { float f; unsigned int u; } a; a.u = ((unsigned int)h) << 16;
  return a.f;
}

__device__ __forceinline__ void gl16(const void* g, void* l) {
  __builtin_amdgcn_global_load_lds(
      (const __attribute__((address_space(1))) unsigned int*)g,
      (__attribute__((address_space(3))) unsigned int*)l, 16, 0, 0);
}

// ---------------- split fp32 -> bf16 hi/lo ----------------
__global__ void k_split(const float* __restrict__ in, unsigned short* __restrict__ hi,
                        unsigned short* __restrict__ lo, int n4) {
  int i = blockIdx.x * blockDim.x + threadIdx.x;
  int stride = gridDim.x * blockDim.x;
  const float4* in4 = (const float4*)in;
  for (; i < n4; i += stride) {
    float4 v = in4[i];
    ushort4 h, l;
    h.x = f2bf(v.x); l.x = f2bf(v.x - bf2f(h.x));
    h.y = f2bf(v.y); l.y = f2bf(v.y - bf2f(h.y));
    h.z = f2bf(v.z); l.z = f2bf(v.z - bf2f(h.z));
    h.w = f2bf(v.w); l.w = f2bf(v.w - bf2f(h.w));
    ((ushort4*)hi)[i] = h;
    ((ushort4*)lo)[i] = l;
  }
}

// ---------------- bf16x3 MFMA GEMM: C = A * B^T + bias ----------------
// A: (M x K) bf16 hi/lo, row-major, K contiguous.  B: (N x K) bf16 hi/lo (= W layout).
// C: (M x N) fp32. Tile 128x128, BK=32, 256 threads = 4 waves (2x2), 4x4 frags 16x16x32.
// LDS layout per tile: slot s = kc*128 + row, 16B per slot ([kc][row]) -> conflict-free frag reads.
__global__ __launch_bounds__(256, 2)
void k_gemm(const unsigned short* __restrict__ Ahi, const unsigned short* __restrict__ Alo,
            const unsigned short* __restrict__ Bhi, const unsigned short* __restrict__ Blo,
            const float* __restrict__ bias, float* __restrict__ C,
            int M, int Nn, int K) {
  const int nbn = Nn >> 7;                 // N tiles
  int bm = blockIdx.x / nbn;
  int bn = blockIdx.x % nbn;

  __shared__ unsigned short lds[16384];    // 32 KB: Ahi,Alo,Bhi,Blo tiles of 4096 ushort
  unsigned short* sAh = lds;
  unsigned short* sAl = lds + 4096;
  unsigned short* sBh = lds + 8192;
  unsigned short* sBl = lds + 12288;

  int tid  = threadIdx.x;
  int lane = tid & 63;
  int wave = tid >> 6;
  int wm = wave >> 1, wn = wave & 1;       // 2x2 wave grid
  int lr = lane & 15;                      // fragment row (16-dim)
  int lk = lane >> 4;                      // k-chunk 0..3 (16B each)

  f32x4 acc[4][4];
#pragma unroll
  for (int i = 0; i < 4; ++i)
#pragma unroll
    for (int j = 0; j < 4; ++j) acc[i][j] = (f32x4){0.f, 0.f, 0.f, 0.f};

  // staging slots: s = kc*128 + row ; global elem offset = (tileRow+row)*K + kc*8
  const int s0 = tid, s1 = tid + 256;
  const int a_r0 = bm * 128 + (s0 & 127), a_r1 = bm * 128 + (s1 & 127);
  const int b_r0 = bn * 128 + (s0 & 127), b_r1 = bn * 128 + (s1 & 127);
  const int a_off0 = a_r0 * K + ((s0 >> 7) << 3);
  const int a_off1 = a_r1 * K + ((s1 >> 7) << 3);
  const int b_off0 = b_r0 * K + ((s0 >> 7) << 3);
  const int b_off1 = b_r1 * K + ((s1 >> 7) << 3);

  for (int k0 = 0; k0 < K; k0 += 32) {
    __syncthreads();                        // protect LDS from previous iter's readers
    gl16(Ahi + a_off0 + k0, sAh + s0 * 8);
    gl16(Ahi + a_off1 + k0, sAh + s1 * 8);
    gl16(Alo + a_off0 + k0, sAl + s0 * 8);
    gl16(Alo + a_off1 + k0, sAl + s1 * 8);
    gl16(Bhi + b_off0 + k0, sBh + s0 * 8);
    gl16(Bhi + b_off1 + k0, sBh + s1 * 8);
    gl16(Blo + b_off0 + k0, sBl + s0 * 8);
    gl16(Blo + b_off1 + k0, sBl + s1 * 8);
    __syncthreads();                        // drains vmcnt before barrier

    bf16x8 ah[4], al[4], bh[4], bl[4];
#pragma unroll
    for (int mi = 0; mi < 4; ++mi) {
      int slot = lk * 128 + wm * 64 + mi * 16 + lr;
      ah[mi] = *(const bf16x8*)(sAh + slot * 8);
      al[mi] = *(const bf16x8*)(sAl + slot * 8);
    }
#pragma unroll
    for (int nj = 0; nj < 4; ++nj) {
      int slot = lk * 128 + wn * 64 + nj * 16 + lr;
      bh[nj] = *(const bf16x8*)(sBh + slot * 8);
      bl[nj] = *(const bf16x8*)(sBl + slot * 8);
    }
    // product passes separated so each acc has 15 other MFMAs between its updates
#pragma unroll
    for (int mi = 0; mi < 4; ++mi)
#pragma unroll
      for (int nj = 0; nj < 4; ++nj)
        acc[mi][nj] = __builtin_amdgcn_mfma_f32_16x16x32_bf16(ah[mi], bh[nj], acc[mi][nj], 0, 0, 0);
#pragma unroll
    for (int mi = 0; mi < 4; ++mi)
#pragma unroll
      for (int nj = 0; nj < 4; ++nj)
        acc[mi][nj] = __builtin_amdgcn_mfma_f32_16x16x32_bf16(ah[mi], bl[nj], acc[mi][nj], 0, 0, 0);
#pragma unroll
    for (int mi = 0; mi < 4; ++mi)
#pragma unroll
      for (int nj = 0; nj < 4; ++nj)
        acc[mi][nj] = __builtin_amdgcn_mfma_f32_16x16x32_bf16(al[mi], bh[nj], acc[mi][nj], 0, 0, 0);
  }

  // epilogue: C/D layout col = lane&15, row = (lane>>4)*4 + r  [HW-verified]
#pragma unroll
  for (int nj = 0; nj < 4; ++nj) {
    int gn = bn * 128 + wn * 64 + nj * 16 + lr;
    float bv = bias[gn];
#pragma unroll
    for (int mi = 0; mi < 4; ++mi) {
      int gm = bm * 128 + wm * 64 + mi * 16 + (lk << 2);
#pragma unroll
      for (int r = 0; r < 4; ++r)
        C[(gm + r) * Nn + gn] = acc[mi][nj][r] + bv;
    }
  }
}

// ---------------- per-channel sum / sumsq over (L*N) rows ----------------
__global__ void k_stats(const float* __restrict__ y, float* __restrict__ sum, float* __restrict__ sq) {
  int t = threadIdx.x;                        // 256 threads; thread owns channels 2t,2t+1
  int rowBase = blockIdx.x * 128;             // 256 blocks x 128 rows
  const float2* p = (const float2*)y + rowBase * 256 + t;
  float s0 = 0.f, s1 = 0.f, q0 = 0.f, q1 = 0.f;
#pragma unroll 8
  for (int r = 0; r < 128; ++r) {
    float2 v = p[r * 256];
    s0 += v.x; s1 += v.y;
    q0 += v.x * v.x; q1 += v.y * v.y;
  }
  atomicAdd(&sum[2 * t], s0);
  atomicAdd(&sum[2 * t + 1], s1);
  atomicAdd(&sq[2 * t], q0);
  atomicAdd(&sq[2 * t + 1], q1);
}

__global__ void k_finalize(const float* __restrict__ sum, const float* __restrict__ sq,
                           const float* __restrict__ g, const float* __restrict__ be,
                           float* __restrict__ scale, float* __restrict__ shift) {
  int c = threadIdx.x;                        // 512 threads
  float m = sum[c] * (1.0f / (float)M_DIM);
  float v = sq[c] * (1.0f / (float)M_DIM) - m * m;  // biased variance (torch norm)
  float sc = g[c] * rsqrtf(v + EPS_BN);
  scale[c] = sc;
  shift[c] = be[c] - m * sc;
}

// ---------------- BN + IndRNN, emit h as bf16 hi/lo for next GEMM ----------------
__global__ __launch_bounds__(64)
void k_indrnn_split(const float* __restrict__ y, const float* __restrict__ scale,
                    const float* __restrict__ shift, const float* __restrict__ u,
                    unsigned short* __restrict__ hhi, unsigned short* __restrict__ hlo) {
  int idx = blockIdx.x * 64 + threadIdx.x;    // (n,c): idx = n*512 + c, 16384 total
  int c = idx & 511;
  float sc = scale[c], sh = shift[c], uu = u[c];
  float h = 0.f;
  const float* py = y + idx;                  // element (l,n,c) at l*16384 + idx
  for (int l0 = 0; l0 < 1024; l0 += 32) {
    float v[32];
#pragma unroll
    for (int i = 0; i < 32; ++i) v[i] = py[(l0 + i) * 16384];
#pragma unroll
    for (int i = 0; i < 32; ++i) {
      float xt = v[i] * sc + sh;
      h = fmaxf(xt + uu * h, 0.f);
      int off = (l0 + i) * 16384 + idx;
      unsigned short hb = f2bf(h);
      hhi[off] = hb;
      hlo[off] = f2bf(h - bf2f(hb));
    }
  }
}

// ---------------- BN + IndRNN + residual, in place on d_out ----------------
__global__ __launch_bounds__(64)
void k_indrnn_res(float* __restrict__ y, const float* __restrict__ x,
                  const float* __restrict__ scale, const float* __restrict__ shift,
                  const float* __restrict__ u) {
  int idx = blockIdx.x * 64 + threadIdx.x;
  int c = idx & 511;
  float sc = scale[c], sh = shift[c], uu = u[c];
  float h = 0.f;
  for (int l0 = 0; l0 < 1024; l0 += 32) {
    float v[32], xs[32];
#pragma unroll
    for (int i = 0; i < 32; ++i) v[i] = y[(l0 + i) * 16384 + idx];
#pragma unroll
    for (int i = 0; i < 32; ++i) xs[i] = x[(l0 + i) * 16384 + idx];
#pragma unroll
    for (int i = 0; i < 32; ++i) {
      float xt = v[i] * sc + sh;
      h = fmaxf(xt + uu * h, 0.f);
      y[(l0 + i) * 16384 + idx] = h + xs[i];
    }
  }
}

extern "C" void kernel_launch(void* const* d_in, const int* in_sizes, int n_in,
                              void* d_out, int out_size, void* d_ws, size_t ws_size,
                              hipStream_t stream) {
  if (n_in < 11) return;
  const float* x   = (const float*)d_in[0];
  const float* W1  = (const float*)d_in[1];
  const float* b1  = (const float*)d_in[2];
  const float* g1  = (const float*)d_in[3];
  const float* be1 = (const float*)d_in[4];
  const float* u1  = (const float*)d_in[5];
  const float* W2  = (const float*)d_in[6];
  const float* b2  = (const float*)d_in[7];
  const float* g2  = (const float*)d_in[8];
  const float* be2 = (const float*)d_in[9];
  const float* u2  = (const float*)d_in[10];
  float* out = (float*)d_out;

  char* ws = (char*)d_ws;
  const size_t SZ_HALF = (size_t)M_DIM * C_DIM * sizeof(unsigned short); // 33,554,432 B
  const size_t SZ_W    = (size_t)C_DIM * C_DIM * sizeof(unsigned short); //    524,288 B
  unsigned short* Ahi  = (unsigned short*)(ws);             // x split; reused as h1 split
  unsigned short* Alo  = (unsigned short*)(ws + SZ_HALF);
  unsigned short* W1hi = (unsigned short*)(ws + 2 * SZ_HALF);
  unsigned short* W1lo = W1hi + C_DIM * C_DIM;
  unsigned short* W2hi = W1lo + C_DIM * C_DIM;
  unsigned short* W2lo = W2hi + C_DIM * C_DIM;
  float* stats = (float*)(ws + 2 * SZ_HALF + 4 * SZ_W);
  float* sum1 = stats,        *sq1 = stats + 512;
  float* sum2 = stats + 1024, *sq2 = stats + 1536;
  float* scale1 = stats + 2048, *shift1 = stats + 2560;
  float* scale2 = stats + 3072, *shift2 = stats + 3584;
  if (ws_size < 2 * SZ_HALF + 4 * SZ_W + 8 * 512 * sizeof(float)) return;

  hipMemsetAsync(stats, 0, 4 * 512 * sizeof(float), stream);  // sum1,sq1,sum2,sq2

  k_split<<<1024, 256, 0, stream>>>(x, Ahi, Alo, M_DIM * C_DIM / 4);
  k_split<<<256, 256, 0, stream>>>(W1, W1hi, W1lo, C_DIM * C_DIM / 4);
  k_split<<<256, 256, 0, stream>>>(W2, W2hi, W2lo, C_DIM * C_DIM / 4);

  dim3 gemmGrid((M_DIM / 128) * (C_DIM / 128));   // 1024 blocks
  k_gemm<<<gemmGrid, 256, 0, stream>>>(Ahi, Alo, W1hi, W1lo, b1, out, M_DIM, C_DIM, C_DIM);
  k_stats<<<256, 256, 0, stream>>>(out, sum1, sq1);
  k_finalize<<<1, 512, 0, stream>>>(sum1, sq1, g1, be1, scale1, shift1);
  k_indrnn_split<<<256, 64, 0, stream>>>(out, scale1, shift1, u1, Ahi, Alo);

  k_gemm<<<gemmGrid, 256, 0, stream>>>(Ahi, Alo, W2hi, W2lo, b2, out, M_DIM, C_DIM, C_DIM);
  k_stats<<<256, 256, 0, stream>>>(out, sum2, sq2);
  k_finalize<<<1, 512, 0, stream>>>(sum2, sq2, g2, be2, scale2, shift2);
  k_indrnn_res<<<256, 64, 0, stream>>>(out, x, scale2, shift2, u2);
}

// Round 2
// 262.860 us; speedup vs baseline: 1.3573x; 1.3573x over previous
//
#include <hip/hip_runtime.h>
#include <stdint.h>

#define L_DIM 1024
#define N_DIM 32
#define C_DIM 512
#define M_DIM (L_DIM * N_DIM)   // 32768 rows for the GEMMs
#define EPS_BN 1e-5f

typedef __attribute__((ext_vector_type(8))) short bf16x8;
typedef __attribute__((ext_vector_type(4))) float f32x4;

__device__ __forceinline__ unsigned short f2bf(float f) {
  union { float f; unsigned int u; } a; a.f = f;
  unsigned int u = a.u;
  return (unsigned short)((u + 0x7FFFu + ((u >> 16) & 1u)) >> 16); // RNE
}
__device__ __forceinline__ float bf2f(unsigned short h) {
  union { float f; unsigned int u; } a; a.u = ((unsigned int)h) << 16;
  return a.f;
}

// trunc-split two floats into packed bf16 hi-pair and lo-pair
__device__ __forceinline__ void split2(float f0, float f1, unsigned int& hi, unsigned int& lo) {
  union { float f; unsigned int u; } a0, a1, t0, t1, b0, b1;
  a0.f = f0; a1.f = f1;
  hi = (a0.u >> 16) | (a1.u & 0xFFFF0000u);
  t0.u = a0.u & 0xFFFF0000u; t1.u = a1.u & 0xFFFF0000u;
  b0.f = f0 - t0.f;          b1.f = f1 - t1.f;      // exact residuals
  lo = (b0.u >> 16) | (b1.u & 0xFFFF0000u);
}

__device__ __forceinline__ void gl16(const void* g, void* l) {
  __builtin_amdgcn_global_load_lds(
      (const __attribute__((address_space(1))) unsigned int*)g,
      (__attribute__((address_space(3))) unsigned int*)l, 16, 0, 0);
}

// ---------------- split fp32 -> bf16 hi/lo (weights only) ----------------
__global__ void k_split(const float* __restrict__ in, unsigned short* __restrict__ hi,
                        unsigned short* __restrict__ lo, int n4) {
  int i = blockIdx.x * blockDim.x + threadIdx.x;
  int stride = gridDim.x * blockDim.x;
  const float4* in4 = (const float4*)in;
  for (; i < n4; i += stride) {
    float4 v = in4[i];
    ushort4 h, l;
    h.x = f2bf(v.x); l.x = f2bf(v.x - bf2f(h.x));
    h.y = f2bf(v.y); l.y = f2bf(v.y - bf2f(h.y));
    h.z = f2bf(v.z); l.z = f2bf(v.z - bf2f(h.z));
    h.w = f2bf(v.w); l.w = f2bf(v.w - bf2f(h.w));
    ((ushort4*)hi)[i] = h;
    ((ushort4*)lo)[i] = l;
  }
}

// ---------------- bf16x3 MFMA GEMM: C = A(fp32) * B^T + bias, fused BN stats ----------------
// A: (M x K) fp32 row-major. B: (N x K) bf16 hi/lo pre-split. C: (M x N) fp32.
// Tile 128x128, BK=32, 256 threads = 4 waves (2x2), 4x4 frags of mfma 16x16x32 bf16, 3 passes.
// LDS: sA fp32 [kc4][row] 16B slots (16KB); sBh/sBl bf16 [kc8][row] 16B slots (8KB each).
// blockIdx swizzle: all 4 bn-blocks of one bm land on the same XCD (round-robin d%8).
__global__ __launch_bounds__(256, 2)
void k_gemm(const float* __restrict__ A,
            const unsigned short* __restrict__ Bhi, const unsigned short* __restrict__ Blo,
            const float* __restrict__ bias, float* __restrict__ C,
            float* __restrict__ gsum, float* __restrict__ gsq,
            int M, int Nn, int K) {
  int d = blockIdx.x;
  int xcd = d & 7;
  int q = d >> 3;                    // 0..127
  int bm = xcd * 32 + (q >> 2);      // 256 A-panels, 32 consecutive per XCD
  int bn = q & 3;

  __shared__ float sA[4096];             // 16 KB: 128x32 fp32, slot = kc4*128+row (4 floats)
  __shared__ unsigned short sBh[4096];   //  8 KB: 128x32 bf16, slot = kc8*128+row (8 elems)
  __shared__ unsigned short sBl[4096];

  int tid  = threadIdx.x;
  int lane = tid & 63;
  int wave = tid >> 6;
  int wm = wave >> 1, wn = wave & 1;
  int lr = lane & 15;
  int lk = lane >> 4;

  f32x4 acc[4][4];
#pragma unroll
  for (int i = 0; i < 4; ++i)
#pragma unroll
    for (int j = 0; j < 4; ++j) acc[i][j] = (f32x4){0.f, 0.f, 0.f, 0.f};

  // A staging: 4 slots/thread (1024 slots of 4 floats)
  const int as0 = tid, as1 = tid + 256, as2 = tid + 512, as3 = tid + 768;
  const int a_off0 = (bm * 128 + (as0 & 127)) * K + ((as0 >> 7) << 2);
  const int a_off1 = (bm * 128 + (as1 & 127)) * K + ((as1 >> 7) << 2);
  const int a_off2 = (bm * 128 + (as2 & 127)) * K + ((as2 >> 7) << 2);
  const int a_off3 = (bm * 128 + (as3 & 127)) * K + ((as3 >> 7) << 2);
  // B staging: 2 slots/thread per matrix (512 slots of 8 bf16)
  const int bs0 = tid, bs1 = tid + 256;
  const int b_off0 = (bn * 128 + (bs0 & 127)) * K + ((bs0 >> 7) << 3);
  const int b_off1 = (bn * 128 + (bs1 & 127)) * K + ((bs1 >> 7) << 3);

  for (int k0 = 0; k0 < K; k0 += 32) {
    __syncthreads();
    gl16(A + a_off0 + k0, sA + as0 * 4);
    gl16(A + a_off1 + k0, sA + as1 * 4);
    gl16(A + a_off2 + k0, sA + as2 * 4);
    gl16(A + a_off3 + k0, sA + as3 * 4);
    gl16(Bhi + b_off0 + k0, sBh + bs0 * 8);
    gl16(Bhi + b_off1 + k0, sBh + bs1 * 8);
    gl16(Blo + b_off0 + k0, sBl + bs0 * 8);
    gl16(Blo + b_off1 + k0, sBl + bs1 * 8);
    __syncthreads();

    bf16x8 ah[4], al[4], bh[4], bl[4];
#pragma unroll
    for (int mi = 0; mi < 4; ++mi) {
      int row = wm * 64 + mi * 16 + lr;
      f32x4 a0 = *(const f32x4*)(sA + ((2 * lk) * 128 + row) * 4);
      f32x4 a1 = *(const f32x4*)(sA + ((2 * lk + 1) * 128 + row) * 4);
      union { unsigned int u[4]; bf16x8 v; } H, Lo;
      split2(a0[0], a0[1], H.u[0], Lo.u[0]);
      split2(a0[2], a0[3], H.u[1], Lo.u[1]);
      split2(a1[0], a1[1], H.u[2], Lo.u[2]);
      split2(a1[2], a1[3], H.u[3], Lo.u[3]);
      ah[mi] = H.v; al[mi] = Lo.v;
    }
#pragma unroll
    for (int nj = 0; nj < 4; ++nj) {
      int slot = lk * 128 + wn * 64 + nj * 16 + lr;
      bh[nj] = *(const bf16x8*)(sBh + slot * 8);
      bl[nj] = *(const bf16x8*)(sBl + slot * 8);
    }
#pragma unroll
    for (int mi = 0; mi < 4; ++mi)
#pragma unroll
      for (int nj = 0; nj < 4; ++nj)
        acc[mi][nj] = __builtin_amdgcn_mfma_f32_16x16x32_bf16(ah[mi], bh[nj], acc[mi][nj], 0, 0, 0);
#pragma unroll
    for (int mi = 0; mi < 4; ++mi)
#pragma unroll
      for (int nj = 0; nj < 4; ++nj)
        acc[mi][nj] = __builtin_amdgcn_mfma_f32_16x16x32_bf16(ah[mi], bl[nj], acc[mi][nj], 0, 0, 0);
#pragma unroll
    for (int mi = 0; mi < 4; ++mi)
#pragma unroll
      for (int nj = 0; nj < 4; ++nj)
        acc[mi][nj] = __builtin_amdgcn_mfma_f32_16x16x32_bf16(al[mi], bh[nj], acc[mi][nj], 0, 0, 0);
  }

  // epilogue: C/D layout col = lane&15, row = (lane>>4)*4 + r; fused bias + BN partial stats
#pragma unroll
  for (int nj = 0; nj < 4; ++nj) {
    int gn = bn * 128 + wn * 64 + nj * 16 + lr;
    float bv = bias[gn];
    float s = 0.f, qq = 0.f;
#pragma unroll
    for (int mi = 0; mi < 4; ++mi) {
      int gm = bm * 128 + wm * 64 + mi * 16 + (lk << 2);
#pragma unroll
      for (int r = 0; r < 4; ++r) {
        float v = acc[mi][nj][r] + bv;
        C[(gm + r) * Nn + gn] = v;
        s += v; qq += v * v;
      }
    }
    // reduce across lk (lanes lr, lr+16, lr+32, lr+48 share gn)
    s  += __shfl_xor(s, 16);  qq += __shfl_xor(qq, 16);
    s  += __shfl_xor(s, 32);  qq += __shfl_xor(qq, 32);
    if (lk == 0) {
      atomicAdd(&gsum[gn], s);
      atomicAdd(&gsq[gn], qq);
    }
  }
}

__global__ void k_finalize(const float* __restrict__ sum, const float* __restrict__ sq,
                           const float* __restrict__ g, const float* __restrict__ be,
                           float* __restrict__ scale, float* __restrict__ shift) {
  int c = threadIdx.x;                        // 512 threads
  float m = sum[c] * (1.0f / (float)M_DIM);
  float v = sq[c] * (1.0f / (float)M_DIM) - m * m;  // biased variance
  float sc = g[c] * rsqrtf(v + EPS_BN);
  scale[c] = sc;
  shift[c] = be[c] - m * sc;
}

// ---------------- BN + IndRNN, emit fp32 h for next GEMM ----------------
__global__ __launch_bounds__(64)
void k_indrnn1(const float* __restrict__ y, const float* __restrict__ scale,
               const float* __restrict__ shift, const float* __restrict__ u,
               float* __restrict__ hout) {
  int idx = blockIdx.x * 64 + threadIdx.x;    // (n,c): idx = n*512 + c, 16384 total
  int c = idx & 511;
  float sc = scale[c], sh = shift[c], uu = u[c];
  float h = 0.f;
  const float* py = y + idx;
  float* ph = hout + idx;
  for (int l0 = 0; l0 < 1024; l0 += 32) {
    float v[32];
#pragma unroll
    for (int i = 0; i < 32; ++i) v[i] = py[(l0 + i) * 16384];
#pragma unroll
    for (int i = 0; i < 32; ++i) {
      float xt = v[i] * sc + sh;
      h = fmaxf(xt + uu * h, 0.f);
      ph[(l0 + i) * 16384] = h;
    }
  }
}

// ---------------- BN + IndRNN + residual, in place on d_out ----------------
__global__ __launch_bounds__(64)
void k_indrnn_res(float* __restrict__ y, const float* __restrict__ x,
                  const float* __restrict__ scale, const float* __restrict__ shift,
                  const float* __restrict__ u) {
  int idx = blockIdx.x * 64 + threadIdx.x;
  int c = idx & 511;
  float sc = scale[c], sh = shift[c], uu = u[c];
  float h = 0.f;
  for (int l0 = 0; l0 < 1024; l0 += 32) {
    float v[32], xs[32];
#pragma unroll
    for (int i = 0; i < 32; ++i) v[i] = y[(l0 + i) * 16384 + idx];
#pragma unroll
    for (int i = 0; i < 32; ++i) xs[i] = x[(l0 + i) * 16384 + idx];
#pragma unroll
    for (int i = 0; i < 32; ++i) {
      float xt = v[i] * sc + sh;
      h = fmaxf(xt + uu * h, 0.f);
      y[(l0 + i) * 16384 + idx] = h + xs[i];
    }
  }
}

extern "C" void kernel_launch(void* const* d_in, const int* in_sizes, int n_in,
                              void* d_out, int out_size, void* d_ws, size_t ws_size,
                              hipStream_t stream) {
  if (n_in < 11) return;
  const float* x   = (const float*)d_in[0];
  const float* W1  = (const float*)d_in[1];
  const float* b1  = (const float*)d_in[2];
  const float* g1  = (const float*)d_in[3];
  const float* be1 = (const float*)d_in[4];
  const float* u1  = (const float*)d_in[5];
  const float* W2  = (const float*)d_in[6];
  const float* b2  = (const float*)d_in[7];
  const float* g2  = (const float*)d_in[8];
  const float* be2 = (const float*)d_in[9];
  const float* u2  = (const float*)d_in[10];
  float* out = (float*)d_out;

  char* ws = (char*)d_ws;
  const size_t SZ_H1 = (size_t)M_DIM * C_DIM * sizeof(float);           // 67,108,864 B
  const size_t SZ_W  = (size_t)C_DIM * C_DIM * sizeof(unsigned short);  //    524,288 B
  float* h1 = (float*)ws;
  unsigned short* W1hi = (unsigned short*)(ws + SZ_H1);
  unsigned short* W1lo = W1hi + C_DIM * C_DIM;
  unsigned short* W2hi = W1lo + C_DIM * C_DIM;
  unsigned short* W2lo = W2hi + C_DIM * C_DIM;
  float* stats = (float*)(ws + SZ_H1 + 4 * SZ_W);
  float* sum1 = stats,        *sq1 = stats + 512;
  float* sum2 = stats + 1024, *sq2 = stats + 1536;
  float* scale1 = stats + 2048, *shift1 = stats + 2560;
  float* scale2 = stats + 3072, *shift2 = stats + 3584;
  if (ws_size < SZ_H1 + 4 * SZ_W + 8 * 512 * sizeof(float)) return;

  hipMemsetAsync(stats, 0, 4 * 512 * sizeof(float), stream);  // sum1,sq1,sum2,sq2

  k_split<<<256, 256, 0, stream>>>(W1, W1hi, W1lo, C_DIM * C_DIM / 4);
  k_split<<<256, 256, 0, stream>>>(W2, W2hi, W2lo, C_DIM * C_DIM / 4);

  dim3 gemmGrid((M_DIM / 128) * (C_DIM / 128));   // 1024 blocks = 8 XCD * 128
  k_gemm<<<gemmGrid, 256, 0, stream>>>(x, W1hi, W1lo, b1, out, sum1, sq1, M_DIM, C_DIM, C_DIM);
  k_finalize<<<1, 512, 0, stream>>>(sum1, sq1, g1, be1, scale1, shift1);
  k_indrnn1<<<256, 64, 0, stream>>>(out, scale1, shift1, u1, h1);

  k_gemm<<<gemmGrid, 256, 0, stream>>>(h1, W2hi, W2lo, b2, out, sum2, sq2, M_DIM, C_DIM, C_DIM);
  k_finalize<<<1, 512, 0, stream>>>(sum2, sq2, g2, be2, scale2, shift2);
  k_indrnn_res<<<256, 64, 0, stream>>>(out, x, scale2, shift2, u2);
}